// Round 9
// baseline (312.210 us; speedup 1.0000x reference)
//
#include <hip/hip_runtime.h>
#include <stdint.h>

// ----------------------------------------------------------------------------
// SparseKVCache: keep top-k by |x| (k = n/2), zero the rest. Exact.
// R9 = R8 (proven correct, 143 us) + TWO DIAGNOSTIC PROBES at the end:
//   probe_copy:     pure uint4 copy x -> ws[128MB..256MB)   (m13 shape)
//   probe_classify: copy + branchless classify + count -> ws[256MB..384MB)
// Probes write only to scratch; algorithm output unchanged. Their per-dispatch
// rocprof rows give the true achievable stream BW in this harness, isolating
// copy vs classify vs hit-machinery cost. Deterministic (counters re-zeroed
// by zero_ws each call).
// ----------------------------------------------------------------------------

#define NTHR 256
#define MASK31 0x7fffffffu

typedef unsigned int v4u __attribute__((ext_vector_type(4)));

// ---- ws layout (uint32 words) ----
#define SH_OFF    0           // 8192-bin sample histogram (bits 30..18)
#define SH_BINS   8192
#define CH_OFF    8192        // 4096-bin candidate histogram
#define CH_BINS   4096
#define SCL_OFF   12288       // scalars:
//  [0]=uLo [1]=uHi [2]=shift1 [3]=cntHi [4]=gCount [5]=base2 [6]=rem2 [7]=c3
//  [15]=probe counter sink
#define L3_OFF    12304       // sub-bin pairs (uint2); even => 8B aligned
#define L3_CAP    4096
#define PAIRS_OFF (L3_OFF + 2 * L3_CAP)    // 20496, even => 8B aligned
#define PAIRS_CAP (1u << 20)               // 1M pairs = 8 MB
#define ZERO_WORDS (SCL_OFF + 16)
#define PROBE1_OFF 33554432LL              // byte offset 128 MB (uint4-aligned)
#define PROBE2_OFF 67108864LL              // byte offset 256 MB

#define STG_CAP   2048        // per-block LDS pair stage (16 KB)

__global__ void zero_ws_kernel(uint32_t* __restrict__ ws) {
    int i = blockIdx.x * blockDim.x + threadIdx.x;
    if (i < ZERO_WORDS) ws[i] = 0;
}

// ---- sample histogram: 128 blocks x 32KB contiguous chunks (1M samples) ----
__global__ void sample_hist_kernel(const uint4* __restrict__ xv, long long n4,
                                   uint32_t* __restrict__ ws) {
    __shared__ uint32_t lh[SH_BINS];
    for (int i = threadIdx.x; i < SH_BINS; i += NTHR) lh[i] = 0;
    __syncthreads();
    long long chunkStride = n4 >> 7;           // 128 chunks across the data
    long long base = (long long)blockIdx.x * chunkStride + threadIdx.x;
    for (int j = 0; j < 8; ++j) {
        long long idx = base + (long long)j * NTHR;
        if (idx < n4) {
            uint4 v = xv[idx];
            atomicAdd(&lh[(v.x & MASK31) >> 18], 1u);
            atomicAdd(&lh[(v.y & MASK31) >> 18], 1u);
            atomicAdd(&lh[(v.z & MASK31) >> 18], 1u);
            atomicAdd(&lh[(v.w & MASK31) >> 18], 1u);
        }
    }
    __syncthreads();
    for (int i = threadIdx.x; i < SH_BINS; i += NTHR)
        if (lh[i]) atomicAdd(&ws[SH_OFF + i], lh[i]);
}

// ---- bracket select from sample histogram -> value-space [uLo, uHi) --------
__global__ void sel_bracket_kernel(uint32_t* __restrict__ ws,
                                   uint32_t ksmM, uint32_t kspM) {
    __shared__ uint32_t lh[SH_BINS];
    __shared__ uint32_t csum[NTHR];
    __shared__ uint32_t cpre[NTHR];
    __shared__ int sBHi, sB1;
    for (int i = threadIdx.x; i < SH_BINS; i += NTHR) lh[i] = ws[SH_OFF + i];
    if (threadIdx.x == 0) { sBHi = -1; sB1 = -1; }
    __syncthreads();
    uint32_t s = 0;
    for (int i = 0; i < 32; ++i) s += lh[threadIdx.x * 32 + i];
    csum[threadIdx.x] = s;
    __syncthreads();
    if (threadIdx.x == 0) {
        uint32_t run = 0;
        for (int c = NTHR - 1; c >= 0; --c) { cpre[c] = run; run += csum[c]; }
    }
    __syncthreads();
    {
        int c = threadIdx.x;
        int hitHi = -1, hitB1 = -1;
        uint32_t excl = cpre[c];
        for (int bb = c * 32 + 31; bb >= c * 32; --bb) {
            uint32_t cnt = lh[bb];
            uint32_t incl = excl + cnt;
            if (hitHi < 0 && incl >= ksmM) hitHi = bb;
            if (hitB1 < 0 && excl >= kspM) hitB1 = bb;
            excl = incl;
        }
        if (hitHi >= 0) atomicMax(&sBHi, hitHi);
        if (hitB1 >= 0) atomicMax(&sB1, hitB1);
    }
    __syncthreads();
    if (threadIdx.x == 0) {
        int bHi = sBHi < 0 ? 0 : sBHi;
        int bLo = sB1 + 1;
        if (bLo > bHi) bLo = bHi;
        if (bLo < 0) bLo = 0;
        int sbins = bHi - bLo + 1;
        int clog = 0; while ((1 << clog) < sbins) ++clog;
        int spanBits = 18 + clog;
        int shift1 = spanBits - 12;            // 4096 bins over the span
        if (shift1 < 0) shift1 = 0;
        ws[SCL_OFF + 0] = ((uint32_t)bLo) << 18;          // uLo
        ws[SCL_OFF + 1] = ((uint32_t)(bHi + 1)) << 18;    // uHi (exclusive)
        ws[SCL_OFF + 2] = (uint32_t)shift1;
    }
}

// ---- fused full pass (R8): 4-slot branchless stream, nt stores -------------
__global__ __launch_bounds__(NTHR, 4)
void fused_main_kernel(const uint32_t* __restrict__ x,
                       uint32_t* __restrict__ out, long long n,
                       uint32_t* __restrict__ ws) {
    __shared__ uint2 stage[STG_CAP];
    __shared__ uint32_t cnt, sBase, redHi[NTHR / 64];
    const uint32_t uLo = ws[SCL_OFF + 0];
    const uint32_t uHi = ws[SCL_OFF + 1];
    const uint32_t span = uHi - uLo;
    if (threadIdx.x == 0) cnt = 0u;
    __syncthreads();

    const v4u* __restrict__ xv = (const v4u*)x;
    v4u* __restrict__ ov = (v4u*)out;
    uint2* __restrict__ gpairs = (uint2*)(ws + PAIRS_OFF);
    long long n4 = n >> 2;
    const long long stride = (long long)gridDim.x * NTHR;
    const long long i0 = (long long)blockIdx.x * NTHR + threadIdx.x;

    uint32_t myHi = 0;
    uint32_t hitMask = 0;
    uint32_t it = 0;
    long long i = i0;

#define CLASS(v, o, hb) { \
    uint32_t c0 = v.x & MASK31, c1 = v.y & MASK31, c2 = v.z & MASK31, c3 = v.w & MASK31; \
    myHi += (uint32_t)(c0 >= uHi) + (uint32_t)(c1 >= uHi) \
          + (uint32_t)(c2 >= uHi) + (uint32_t)(c3 >= uHi); \
    o.x = (c0 >= uHi) ? v.x : 0u; o.y = (c1 >= uHi) ? v.y : 0u; \
    o.z = (c2 >= uHi) ? v.z : 0u; o.w = (c3 >= uHi) ? v.w : 0u; \
    hb = (uint32_t)((c0 - uLo) < span) | (uint32_t)((c1 - uLo) < span) \
       | (uint32_t)((c2 - uLo) < span) | (uint32_t)((c3 - uLo) < span); }

    for (; i + 3 * stride < n4; i += 4 * stride, it += 4) {
        v4u v0 = xv[i];
        v4u v1 = xv[i + stride];
        v4u v2 = xv[i + 2 * stride];
        v4u v3 = xv[i + 3 * stride];
        v4u o0, o1, o2, o3;
        uint32_t h0, h1, h2, h3;
        CLASS(v0, o0, h0) CLASS(v1, o1, h1) CLASS(v2, o2, h2) CLASS(v3, o3, h3)
        hitMask |= h0 << (it & 31);
        hitMask |= h1 << ((it + 1) & 31);
        hitMask |= h2 << ((it + 2) & 31);
        hitMask |= h3 << ((it + 3) & 31);
        __builtin_nontemporal_store(o0, &ov[i]);
        __builtin_nontemporal_store(o1, &ov[i + stride]);
        __builtin_nontemporal_store(o2, &ov[i + 2 * stride]);
        __builtin_nontemporal_store(o3, &ov[i + 3 * stride]);
    }
    for (; i < n4; i += stride, ++it) {
        v4u v = xv[i];
        v4u o;
        uint32_t hb;
        CLASS(v, o, hb)
        hitMask |= hb << (it & 31);
        __builtin_nontemporal_store(o, &ov[i]);
    }
#undef CLASS

#define PUSHP(val, eidx) { \
    uint32_t p_ = atomicAdd(&cnt, 1u); \
    uint2 pr_ = make_uint2((val), (eidx)); \
    if (p_ < STG_CAP) stage[p_] = pr_; \
    else { uint32_t g_ = atomicAdd(&ws[SCL_OFF + 4], 1u); \
           if (g_ < PAIRS_CAP) gpairs[g_] = pr_; } }

    if (blockIdx.x == 0) {
        for (long long idx = (n4 << 2) + threadIdx.x; idx < n; idx += NTHR) {
            uint32_t v = x[idx];
            uint32_t u = v & MASK31;
            myHi += (uint32_t)(u >= uHi);
            if (u - uLo < span) PUSHP(v, (uint32_t)idx)
            out[idx] = (u >= uHi) ? v : 0u;
        }
    }

    while (hitMask) {
        uint32_t b = __ffs(hitMask) - 1u;
        hitMask &= hitMask - 1u;
        for (long long ii = i0 + (long long)b * stride; ii < n4; ii += (stride << 5)) {
            v4u v = xv[ii];
            uint32_t e0 = (uint32_t)(ii << 2);
            uint32_t u;
            u = v.x & MASK31; if (u - uLo < span) PUSHP(v.x, e0 + 0u)
            u = v.y & MASK31; if (u - uLo < span) PUSHP(v.y, e0 + 1u)
            u = v.z & MASK31; if (u - uLo < span) PUSHP(v.z, e0 + 2u)
            u = v.w & MASK31; if (u - uLo < span) PUSHP(v.w, e0 + 3u)
        }
    }
#undef PUSHP

    for (int o = 32; o > 0; o >>= 1) myHi += __shfl_down(myHi, o);
    if ((threadIdx.x & 63) == 0) redHi[threadIdx.x >> 6] = myHi;
    __syncthreads();
    if (threadIdx.x == 0) {
        uint32_t tot = 0;
        for (int w = 0; w < NTHR / 64; ++w) tot += redHi[w];
        if (tot) atomicAdd(&ws[SCL_OFF + 3], tot);
        uint32_t c = cnt < STG_CAP ? cnt : STG_CAP;
        cnt = c;
        sBase = atomicAdd(&ws[SCL_OFF + 4], c);
    }
    __syncthreads();
    uint32_t c = cnt, bw = sBase;
    for (uint32_t q = threadIdx.x; q < c; q += NTHR)
        if (bw + q < PAIRS_CAP) gpairs[bw + q] = stage[q];
}

// ---- candidate histogram (4096 bins over bracket) ---------------------------
__global__ void cand_hist_kernel(uint32_t* __restrict__ ws) {
    __shared__ uint32_t lh[CH_BINS];
    uint32_t G = ws[SCL_OFF + 4]; if (G > PAIRS_CAP) G = PAIRS_CAP;
    uint32_t uLo = ws[SCL_OFF + 0], shift1 = ws[SCL_OFF + 2];
    for (int i = threadIdx.x; i < CH_BINS; i += NTHR) lh[i] = 0;
    __syncthreads();
    const uint2* pairs = (const uint2*)(ws + PAIRS_OFF);
    uint32_t stride = gridDim.x * NTHR;
    for (uint32_t i = blockIdx.x * NTHR + threadIdx.x; i < G; i += stride) {
        uint32_t u = pairs[i].x & MASK31;
        atomicAdd(&lh[((u - uLo) >> shift1) & (CH_BINS - 1)], 1u);
    }
    __syncthreads();
    for (int i = threadIdx.x; i < CH_BINS; i += NTHR)
        if (lh[i]) atomicAdd(&ws[CH_OFF + i], lh[i]);
}

// ---- sub-bin select (redundant per block) + gather in-bin pairs -------------
__global__ void sel_gather_kernel(uint32_t* __restrict__ ws, uint32_t k) {
    __shared__ uint32_t lh[CH_BINS];
    __shared__ uint32_t csum[NTHR];
    __shared__ uint32_t cpre[NTHR];
    __shared__ uint32_t sBase2, sRem2, sKp;
    for (int i = threadIdx.x; i < CH_BINS; i += NTHR) lh[i] = ws[CH_OFF + i];
    __syncthreads();
    uint32_t s = 0;
    for (int i = 0; i < 16; ++i) s += lh[threadIdx.x * 16 + i];
    csum[threadIdx.x] = s;
    __syncthreads();
    if (threadIdx.x == 0) {
        uint32_t run = 0;
        for (int c = NTHR - 1; c >= 0; --c) { cpre[c] = run; run += csum[c]; }
        uint32_t cntHi = ws[SCL_OFF + 3];
        uint32_t total = cpre[0] + csum[0];
        uint32_t kp = (k > cntHi) ? (k - cntHi) : 1u;
        if (kp > total) kp = total;
        if (kp < 1u) kp = 1u;
        sKp = kp;
    }
    __syncthreads();
    uint32_t kp = sKp;
    if (cpre[threadIdx.x] < kp && kp <= cpre[threadIdx.x] + csum[threadIdx.x]) {
        uint32_t excl = cpre[threadIdx.x];
        for (int bb = threadIdx.x * 16 + 15; bb >= threadIdx.x * 16; --bb) {
            uint32_t cnt = lh[bb];
            if (excl + cnt >= kp) {
                sBase2 = ws[SCL_OFF + 0] + (((uint32_t)bb) << ws[SCL_OFF + 2]);
                sRem2 = kp - excl;
                break;
            }
            excl += cnt;
        }
    }
    __syncthreads();
    if (threadIdx.x == 0) { ws[SCL_OFF + 5] = sBase2; ws[SCL_OFF + 6] = sRem2; }
    uint32_t base2 = sBase2;
    uint32_t width = 1u << ws[SCL_OFF + 2];
    uint32_t G = ws[SCL_OFF + 4]; if (G > PAIRS_CAP) G = PAIRS_CAP;
    const uint2* pairs = (const uint2*)(ws + PAIRS_OFF);
    uint2* l3 = (uint2*)(ws + L3_OFF);
    uint32_t stride = gridDim.x * NTHR;
    for (uint32_t i = blockIdx.x * NTHR + threadIdx.x; i < G; i += stride) {
        uint2 pr = pairs[i];
        uint32_t u = pr.x & MASK31;
        if (u - base2 < width) {
            uint32_t p = atomicAdd(&ws[SCL_OFF + 7], 1u);
            if (p < L3_CAP) l3[p] = pr;
        }
    }
}

// ---- final fixup: restore above-sub-bin pairs; exact stable rank in-bin ----
__global__ void final_fixup_kernel(uint32_t* __restrict__ ws,
                                   uint32_t* __restrict__ out) {
    __shared__ uint2 l3s[L3_CAP];   // 32 KB
    uint32_t c3 = ws[SCL_OFF + 7]; if (c3 > L3_CAP) c3 = L3_CAP;
    uint32_t base2 = ws[SCL_OFF + 5], rem2 = ws[SCL_OFF + 6];
    uint32_t width = 1u << ws[SCL_OFF + 2];
    uint32_t tHi2 = base2 + width;
    const uint2* l3 = (const uint2*)(ws + L3_OFF);
    for (uint32_t q = threadIdx.x; q < c3; q += NTHR) l3s[q] = l3[q];
    __syncthreads();
    uint32_t G = ws[SCL_OFF + 4]; if (G > PAIRS_CAP) G = PAIRS_CAP;
    const uint2* pairs = (const uint2*)(ws + PAIRS_OFF);
    uint32_t stride = gridDim.x * NTHR;
    for (uint32_t i = blockIdx.x * NTHR + threadIdx.x; i < G; i += stride) {
        uint2 pr = pairs[i];
        uint32_t u = pr.x & MASK31;
        if (u >= tHi2) {
            out[pr.y] = pr.x;
        } else if (u - base2 < width) {
            uint32_t rank = 0;
            for (uint32_t p = 0; p < c3; ++p) {
                uint2 q2 = l3s[p];
                uint32_t up = q2.x & MASK31;
                rank += (up > u || (up == u && q2.y < pr.y)) ? 1u : 0u;
            }
            if (rank < rem2) out[pr.y] = pr.x;
        }
    }
}

// ---- PROBE 1: pure uint4 copy, m13 shape ------------------------------------
__global__ void probe_copy_kernel(const v4u* __restrict__ xv,
                                  v4u* __restrict__ dst, long long n4) {
    long long stride = (long long)gridDim.x * NTHR;
    for (long long i = (long long)blockIdx.x * NTHR + threadIdx.x; i < n4; i += stride)
        dst[i] = xv[i];
}

// ---- PROBE 2: copy + branchless classify + count (no hit machinery) --------
__global__ void probe_classify_kernel(const v4u* __restrict__ xv,
                                      v4u* __restrict__ dst, long long n4,
                                      uint32_t* __restrict__ ws) {
    const uint32_t uHi = ws[SCL_OFF + 1];
    uint32_t myHi = 0;
    long long stride = (long long)gridDim.x * NTHR;
    for (long long i = (long long)blockIdx.x * NTHR + threadIdx.x; i < n4; i += stride) {
        v4u v = xv[i];
        uint32_t c0 = v.x & MASK31, c1 = v.y & MASK31;
        uint32_t c2 = v.z & MASK31, c3 = v.w & MASK31;
        myHi += (uint32_t)(c0 >= uHi) + (uint32_t)(c1 >= uHi)
              + (uint32_t)(c2 >= uHi) + (uint32_t)(c3 >= uHi);
        v4u o;
        o.x = (c0 >= uHi) ? v.x : 0u;
        o.y = (c1 >= uHi) ? v.y : 0u;
        o.z = (c2 >= uHi) ? v.z : 0u;
        o.w = (c3 >= uHi) ? v.w : 0u;
        dst[i] = o;
    }
    for (int o = 32; o > 0; o >>= 1) myHi += __shfl_down(myHi, o);
    if ((threadIdx.x & 63) == 0 && myHi) atomicAdd(&ws[SCL_OFF + 15], myHi);
}

extern "C" void kernel_launch(void* const* d_in, const int* in_sizes, int n_in,
                              void* d_out, int out_size, void* d_ws, size_t ws_size,
                              hipStream_t stream) {
    const uint32_t* x = (const uint32_t*)d_in[0];
    uint32_t* out = (uint32_t*)d_out;
    uint32_t* ws = (uint32_t*)d_ws;
    long long n = (long long)in_sizes[0];

    const double ratio = 0.5;  // SPARSE_COMPRESSION_RATIO
    long long k = (long long)((double)n * (1.0 - ratio));
    if (k < 1) k = 1;
    if (k > n) k = n;

    long long n4 = n >> 2;
    long long S = ((n4 >> 7) >= 2048) ? (128LL * NTHR * 8 * 4)   // 1M samples
                                      : (n4 << 2);
    long long ks = (long long)((double)k * ((double)S / (double)n));
    const long long M = 4500;               // ~9 sigma at S=1,048,576
    uint32_t ksmM = (uint32_t)((ks - M) < 1 ? 1 : (ks - M));
    uint32_t kspM = (uint32_t)((ks + M) > S ? S : (ks + M));

    long long nBlk = (n4 + (long long)NTHR * 16 - 1) / ((long long)NTHR * 16);
    if (nBlk < 1) nBlk = 1;
    if (nBlk > 8192) nBlk = 8192;
    int grid = (int)nBlk;

    zero_ws_kernel<<<(ZERO_WORDS + NTHR - 1) / NTHR, NTHR, 0, stream>>>(ws);
    sample_hist_kernel<<<128, NTHR, 0, stream>>>((const uint4*)x, n4, ws);
    sel_bracket_kernel<<<1, NTHR, 0, stream>>>(ws, ksmM, kspM);
    fused_main_kernel<<<grid, NTHR, 0, stream>>>(x, out, n, ws);
    cand_hist_kernel<<<256, NTHR, 0, stream>>>(ws);
    sel_gather_kernel<<<256, NTHR, 0, stream>>>(ws, (uint32_t)k);
    final_fixup_kernel<<<256, NTHR, 0, stream>>>(ws, out);

    // ---- diagnostic probes (scratch-only writes; removed next round) ----
    v4u* probe1 = (v4u*)(ws + PROBE1_OFF);
    v4u* probe2 = (v4u*)(ws + PROBE2_OFF);
    probe_copy_kernel<<<grid, NTHR, 0, stream>>>((const v4u*)x, probe1, n4);
    probe_classify_kernel<<<grid, NTHR, 0, stream>>>((const v4u*)x, probe2, n4, ws);
}

// Round 10
// 143.754 us; speedup vs baseline: 2.1718x; 2.1718x over previous
//
#include <hip/hip_runtime.h>
#include <stdint.h>

// ----------------------------------------------------------------------------
// SparseKVCache: keep top-k by |x| (k = n/2), zero the rest. Exact.
// R10: R9's probes showed pure copy = 5.6 TB/s but same-address global
// atomics serialize (~22cyc each; 8192 of them = +75us). This round removes
// ALL same-address global atomics from hot paths: per-block plain-store
// counters (HIC/PCN) + private per-block pair segments; refine chain reads
// the segmented layout. Sampled bracket (1/8 data) -> fused branchless pass
// (4-slot, nt stores, deferred rare gather) -> cand hist -> sub-bin select +
// segmented gather -> exact stable-rank fixup (ties: smallest index).
// ----------------------------------------------------------------------------

#define NTHR 256
#define MASK31 0x7fffffffu

typedef unsigned int v4u __attribute__((ext_vector_type(4)));

// ---- ws layout (uint32 words) ----
#define SH_OFF    0            // 8192-bin sample histogram (bits 30..18)
#define SH_BINS   8192
#define CH_OFF    8192         // 4096-bin candidate histogram
#define CH_BINS   4096
#define SCL_OFF   12288        // scalars:
//  [0]=uLo [1]=uHi [2]=shift1 [3]=base2 [4]=rem2 [5]=ovfPairCnt [6]=ovfL3Cnt
#define ZERO_WORDS (SCL_OFF + 32)          // SH + CH + SCL
#define HIC_OFF   12320        // per-block hi counts (2048)
#define PCN_OFF   14368        // per-block pair counts (2048)
#define L3C_OFF   16416        // per-block l3 counts (256)
#define L3S_OFF   16672        // l3 segments: 256 x 64 pairs (even => 8B ok)
#define L3SEG_CAP 64
#define OVFP_OFF  49440        // overflow pairs (even)
#define OVFP_CAP  16384
#define OVL3_OFF  90000        // overflow l3 pairs (even)
#define OVL3_CAP  2048
#define PAIRS_OFF 131072       // per-block pair segments: 2048 x 2048 pairs
#define SEG_CAP   2048
#define NBLK_MAIN 2048

__global__ void zero_ws_kernel(uint32_t* __restrict__ ws) {
    int i = blockIdx.x * blockDim.x + threadIdx.x;
    if (i < ZERO_WORDS) ws[i] = 0;
}

// ---- sample histogram: 1/8 of data, contiguous 8KB runs --------------------
__global__ void sample_hist_kernel(const v4u* __restrict__ xv, long long n4,
                                   uint32_t* __restrict__ ws) {
    __shared__ uint32_t lh[SH_BINS];
    for (int i = threadIdx.x; i < SH_BINS; i += NTHR) lh[i] = 0;
    __syncthreads();
    long long S4 = n4 >> 3;                 // sampled uint4 count (1/8)
    long long T = (long long)gridDim.x * NTHR;
    for (long long s = (long long)blockIdx.x * NTHR + threadIdx.x; s < S4; s += T) {
        long long idx4 = ((s >> 9) << 12) | (s & 511);  // 512-uint4 runs / 4096
        if (idx4 < n4) {
            v4u v = xv[idx4];
            atomicAdd(&lh[(v.x & MASK31) >> 18], 1u);
            atomicAdd(&lh[(v.y & MASK31) >> 18], 1u);
            atomicAdd(&lh[(v.z & MASK31) >> 18], 1u);
            atomicAdd(&lh[(v.w & MASK31) >> 18], 1u);
        }
    }
    __syncthreads();
    for (int i = threadIdx.x; i < SH_BINS; i += NTHR)
        if (lh[i]) atomicAdd(&ws[SH_OFF + i], lh[i]);   // scattered addrs: ok
}

// ---- bracket select from sample histogram -> value-space [uLo, uHi) --------
__global__ void sel_bracket_kernel(uint32_t* __restrict__ ws,
                                   uint32_t ksmM, uint32_t kspM) {
    __shared__ uint32_t lh[SH_BINS];
    __shared__ uint32_t csum[NTHR];
    __shared__ uint32_t cpre[NTHR];
    __shared__ int sBHi, sB1;
    for (int i = threadIdx.x; i < SH_BINS; i += NTHR) lh[i] = ws[SH_OFF + i];
    if (threadIdx.x == 0) { sBHi = -1; sB1 = -1; }
    __syncthreads();
    uint32_t s = 0;
    for (int i = 0; i < 32; ++i) s += lh[threadIdx.x * 32 + i];
    csum[threadIdx.x] = s;
    __syncthreads();
    if (threadIdx.x == 0) {
        uint32_t run = 0;
        for (int c = NTHR - 1; c >= 0; --c) { cpre[c] = run; run += csum[c]; }
    }
    __syncthreads();
    {
        int c = threadIdx.x;
        int hitHi = -1, hitB1 = -1;
        uint32_t excl = cpre[c];
        for (int bb = c * 32 + 31; bb >= c * 32; --bb) {
            uint32_t cnt = lh[bb];
            uint32_t incl = excl + cnt;
            if (hitHi < 0 && incl >= ksmM) hitHi = bb;
            if (hitB1 < 0 && excl >= kspM) hitB1 = bb;
            excl = incl;
        }
        if (hitHi >= 0) atomicMax(&sBHi, hitHi);
        if (hitB1 >= 0) atomicMax(&sB1, hitB1);
    }
    __syncthreads();
    if (threadIdx.x == 0) {
        int bHi = sBHi < 0 ? 0 : sBHi;
        int bLo = sB1 + 1;
        if (bLo > bHi) bLo = bHi;
        if (bLo < 0) bLo = 0;
        int sbins = bHi - bLo + 1;
        int clog = 0; while ((1 << clog) < sbins) ++clog;
        int spanBits = 18 + clog;
        int shift1 = spanBits - 12;            // 4096 bins over the span
        if (shift1 < 0) shift1 = 0;
        ws[SCL_OFF + 0] = ((uint32_t)bLo) << 18;          // uLo
        ws[SCL_OFF + 1] = ((uint32_t)(bHi + 1)) << 18;    // uHi (exclusive)
        ws[SCL_OFF + 2] = (uint32_t)shift1;
    }
}

// ---- fused full pass: atomic-free common path -------------------------------
__global__ void fused_main_kernel(const uint32_t* __restrict__ x,
                                  uint32_t* __restrict__ out, long long n,
                                  uint32_t* __restrict__ ws) {
    __shared__ uint2 stage[SEG_CAP];     // 16 KB
    __shared__ uint32_t cnt, redHi[NTHR / 64];
    const uint32_t uLo = ws[SCL_OFF + 0];
    const uint32_t uHi = ws[SCL_OFF + 1];
    const uint32_t span = uHi - uLo;
    if (threadIdx.x == 0) cnt = 0u;
    __syncthreads();

    const v4u* __restrict__ xv = (const v4u*)x;
    v4u* __restrict__ ov = (v4u*)out;
    long long n4 = n >> 2;
    const long long stride = (long long)gridDim.x * NTHR;
    const long long i0 = (long long)blockIdx.x * NTHR + threadIdx.x;

    uint32_t myHi = 0;
    uint32_t hitMask = 0;
    uint32_t it = 0;
    long long i = i0;

#define CLASS(v, o, hb) { \
    uint32_t c0 = v.x & MASK31, c1 = v.y & MASK31, c2 = v.z & MASK31, c3 = v.w & MASK31; \
    myHi += (uint32_t)(c0 >= uHi) + (uint32_t)(c1 >= uHi) \
          + (uint32_t)(c2 >= uHi) + (uint32_t)(c3 >= uHi); \
    o.x = (c0 >= uHi) ? v.x : 0u; o.y = (c1 >= uHi) ? v.y : 0u; \
    o.z = (c2 >= uHi) ? v.z : 0u; o.w = (c3 >= uHi) ? v.w : 0u; \
    hb = (uint32_t)((c0 - uLo) < span) | (uint32_t)((c1 - uLo) < span) \
       | (uint32_t)((c2 - uLo) < span) | (uint32_t)((c3 - uLo) < span); }

    for (; i + 3 * stride < n4; i += 4 * stride, it += 4) {
        v4u v0 = xv[i];
        v4u v1 = xv[i + stride];
        v4u v2 = xv[i + 2 * stride];
        v4u v3 = xv[i + 3 * stride];
        v4u o0, o1, o2, o3;
        uint32_t h0, h1, h2, h3;
        CLASS(v0, o0, h0) CLASS(v1, o1, h1) CLASS(v2, o2, h2) CLASS(v3, o3, h3)
        hitMask |= h0 << (it & 31);
        hitMask |= h1 << ((it + 1) & 31);
        hitMask |= h2 << ((it + 2) & 31);
        hitMask |= h3 << ((it + 3) & 31);
        __builtin_nontemporal_store(o0, &ov[i]);
        __builtin_nontemporal_store(o1, &ov[i + stride]);
        __builtin_nontemporal_store(o2, &ov[i + 2 * stride]);
        __builtin_nontemporal_store(o3, &ov[i + 3 * stride]);
    }
    for (; i < n4; i += stride, ++it) {
        v4u v = xv[i];
        v4u o;
        uint32_t hb;
        CLASS(v, o, hb)
        hitMask |= hb << (it & 31);
        __builtin_nontemporal_store(o, &ov[i]);
    }
#undef CLASS

    uint2* __restrict__ ovfp = (uint2*)(ws + OVFP_OFF);
#define PUSHP(val, eidx) { \
    uint32_t p_ = atomicAdd(&cnt, 1u); \
    uint2 pr_ = make_uint2((val), (eidx)); \
    if (p_ < SEG_CAP) stage[p_] = pr_; \
    else { uint32_t g_ = atomicAdd(&ws[SCL_OFF + 5], 1u); \
           if (g_ < OVFP_CAP) ovfp[g_] = pr_; } }

    // scalar tail (n & 3), block 0
    if (blockIdx.x == 0) {
        for (long long idx = (n4 << 2) + threadIdx.x; idx < n; idx += NTHR) {
            uint32_t v = x[idx];
            uint32_t u = v & MASK31;
            myHi += (uint32_t)(u >= uHi);
            if (u - uLo < span) PUSHP(v, (uint32_t)idx)
            out[idx] = (u >= uHi) ? v : 0u;
        }
    }

    // rare path: revisit flagged iterations (L2/L3-hot reloads)
    while (hitMask) {
        uint32_t b = __ffs(hitMask) - 1u;
        hitMask &= hitMask - 1u;
        for (long long ii = i0 + (long long)b * stride; ii < n4; ii += (stride << 5)) {
            v4u v = xv[ii];
            uint32_t e0 = (uint32_t)(ii << 2);
            uint32_t u;
            u = v.x & MASK31; if (u - uLo < span) PUSHP(v.x, e0 + 0u)
            u = v.y & MASK31; if (u - uLo < span) PUSHP(v.y, e0 + 1u)
            u = v.z & MASK31; if (u - uLo < span) PUSHP(v.z, e0 + 2u)
            u = v.w & MASK31; if (u - uLo < span) PUSHP(v.w, e0 + 3u)
        }
    }
#undef PUSHP

    // block-level hi-count reduce -> PLAIN store (no global atomic)
    for (int o = 32; o > 0; o >>= 1) myHi += __shfl_down(myHi, o);
    if ((threadIdx.x & 63) == 0) redHi[threadIdx.x >> 6] = myHi;
    __syncthreads();
    if (threadIdx.x == 0) {
        uint32_t tot = 0;
        for (int w = 0; w < NTHR / 64; ++w) tot += redHi[w];
        ws[HIC_OFF + blockIdx.x] = tot;
        uint32_t c = cnt < SEG_CAP ? cnt : SEG_CAP;
        cnt = c;
        ws[PCN_OFF + blockIdx.x] = c;
    }
    __syncthreads();
    // flush stage to this block's private segment (plain stores)
    uint2* __restrict__ seg = (uint2*)(ws + PAIRS_OFF) + (size_t)blockIdx.x * SEG_CAP;
    uint32_t c = cnt;
    for (uint32_t q = threadIdx.x; q < c; q += NTHR) seg[q] = stage[q];
}

// ---- candidate histogram over segmented pairs -------------------------------
__global__ void cand_hist_kernel(uint32_t* __restrict__ ws) {
    __shared__ uint32_t lh[CH_BINS];
    uint32_t uLo = ws[SCL_OFF + 0], shift1 = ws[SCL_OFF + 2];
    for (int i = threadIdx.x; i < CH_BINS; i += NTHR) lh[i] = 0;
    __syncthreads();
    const uint2* pairs = (const uint2*)(ws + PAIRS_OFF);
    for (int g = 0; g < NBLK_MAIN / 256; ++g) {
        uint32_t sidx = blockIdx.x + (uint32_t)g * 256u;
        uint32_t c = ws[PCN_OFF + sidx];
        const uint2* seg = pairs + (size_t)sidx * SEG_CAP;
        for (uint32_t i = threadIdx.x; i < c; i += NTHR) {
            uint32_t u = seg[i].x & MASK31;
            atomicAdd(&lh[((u - uLo) >> shift1) & (CH_BINS - 1)], 1u);
        }
    }
    if (blockIdx.x == 0) {   // overflow pairs
        uint32_t c = ws[SCL_OFF + 5]; if (c > OVFP_CAP) c = OVFP_CAP;
        const uint2* ovfp = (const uint2*)(ws + OVFP_OFF);
        for (uint32_t i = threadIdx.x; i < c; i += NTHR) {
            uint32_t u = ovfp[i].x & MASK31;
            atomicAdd(&lh[((u - uLo) >> shift1) & (CH_BINS - 1)], 1u);
        }
    }
    __syncthreads();
    for (int i = threadIdx.x; i < CH_BINS; i += NTHR)
        if (lh[i]) atomicAdd(&ws[CH_OFF + i], lh[i]);   // scattered addrs
}

// ---- sub-bin select (redundant per block) + segmented in-bin gather ---------
__global__ void sel_gather_kernel(uint32_t* __restrict__ ws, uint32_t k) {
    __shared__ uint32_t lh[CH_BINS];
    __shared__ uint32_t csum[NTHR];
    __shared__ uint32_t cpre[NTHR];
    __shared__ uint32_t sBase2, sRem2, sKp, lcnt;
    // cntHi: every block sums HIC[] redundantly (8 KB from L2)
    uint32_t part = 0;
    for (int i = threadIdx.x; i < NBLK_MAIN; i += NTHR) part += ws[HIC_OFF + i];
    for (int o = 32; o > 0; o >>= 1) part += __shfl_down(part, o);
    for (int i = threadIdx.x; i < CH_BINS; i += NTHR) lh[i] = ws[CH_OFF + i];
    if (threadIdx.x == 0) lcnt = 0;
    csum[threadIdx.x] = 0;
    __syncthreads();
    if ((threadIdx.x & 63) == 0) csum[threadIdx.x >> 6] = part;
    __syncthreads();
    uint32_t cntHi = csum[0] + csum[1] + csum[2] + csum[3];
    __syncthreads();
    uint32_t s = 0;
    for (int i = 0; i < 16; ++i) s += lh[threadIdx.x * 16 + i];
    csum[threadIdx.x] = s;
    __syncthreads();
    if (threadIdx.x == 0) {
        uint32_t run = 0;
        for (int c = NTHR - 1; c >= 0; --c) { cpre[c] = run; run += csum[c]; }
        uint32_t total = cpre[0] + csum[0];
        uint32_t kp = (k > cntHi) ? (k - cntHi) : 1u;
        if (kp > total) kp = total;
        if (kp < 1u) kp = 1u;
        sKp = kp;
    }
    __syncthreads();
    uint32_t kp = sKp;
    if (cpre[threadIdx.x] < kp && kp <= cpre[threadIdx.x] + csum[threadIdx.x]) {
        uint32_t excl = cpre[threadIdx.x];
        for (int bb = threadIdx.x * 16 + 15; bb >= threadIdx.x * 16; --bb) {
            uint32_t cnt = lh[bb];
            if (excl + cnt >= kp) {
                sBase2 = ws[SCL_OFF + 0] + (((uint32_t)bb) << ws[SCL_OFF + 2]);
                sRem2 = kp - excl;
                break;
            }
            excl += cnt;
        }
    }
    __syncthreads();
    if (threadIdx.x == 0) { ws[SCL_OFF + 3] = sBase2; ws[SCL_OFF + 4] = sRem2; }
    // gather in-bin pairs from my 8 segments into my private l3 segment
    uint32_t base2 = sBase2;
    uint32_t width = 1u << ws[SCL_OFF + 2];
    const uint2* pairs = (const uint2*)(ws + PAIRS_OFF);
    uint2* myl3 = (uint2*)(ws + L3S_OFF) + (size_t)blockIdx.x * L3SEG_CAP;
    uint2* ovl3 = (uint2*)(ws + OVL3_OFF);
    __shared__ uint2 lstage[L3SEG_CAP];
    for (int g = 0; g < NBLK_MAIN / 256; ++g) {
        uint32_t sidx = blockIdx.x + (uint32_t)g * 256u;
        uint32_t c = ws[PCN_OFF + sidx];
        const uint2* seg = pairs + (size_t)sidx * SEG_CAP;
        for (uint32_t i = threadIdx.x; i < c; i += NTHR) {
            uint2 pr = seg[i];
            if ((pr.x & MASK31) - base2 < width) {
                uint32_t p = atomicAdd(&lcnt, 1u);   // LDS atomic: cheap
                if (p < L3SEG_CAP) lstage[p] = pr;
                else { uint32_t g2 = atomicAdd(&ws[SCL_OFF + 6], 1u);
                       if (g2 < OVL3_CAP) ovl3[g2] = pr; }
            }
        }
    }
    if (blockIdx.x == 0) {   // overflow pairs
        uint32_t c = ws[SCL_OFF + 5]; if (c > OVFP_CAP) c = OVFP_CAP;
        const uint2* ovfp = (const uint2*)(ws + OVFP_OFF);
        for (uint32_t i = threadIdx.x; i < c; i += NTHR) {
            uint2 pr = ovfp[i];
            if ((pr.x & MASK31) - base2 < width) {
                uint32_t p = atomicAdd(&lcnt, 1u);
                if (p < L3SEG_CAP) lstage[p] = pr;
                else { uint32_t g2 = atomicAdd(&ws[SCL_OFF + 6], 1u);
                       if (g2 < OVL3_CAP) ovl3[g2] = pr; }
            }
        }
    }
    __syncthreads();
    uint32_t c = lcnt < L3SEG_CAP ? lcnt : L3SEG_CAP;
    if (threadIdx.x == 0) ws[L3C_OFF + blockIdx.x] = c;
    for (uint32_t q = threadIdx.x; q < c; q += NTHR) myl3[q] = lstage[q];
}

// ---- final fixup: exact stable rank for in-bin, restore definite keeps -----
#define L3TOT_CAP 4096
__global__ void final_fixup_kernel(uint32_t* __restrict__ ws,
                                   uint32_t* __restrict__ out) {
    __shared__ uint2 l3s[L3TOT_CAP];   // 32 KB
    __shared__ uint32_t tc;
    uint32_t base2 = ws[SCL_OFF + 3], rem2 = ws[SCL_OFF + 4];
    uint32_t width = 1u << ws[SCL_OFF + 2];
    uint32_t tHi2 = base2 + width;
    if (threadIdx.x == 0) tc = 0;
    __syncthreads();
    // collect the complete in-bin set (segments + overflow) into LDS
    const uint2* l3seg = (const uint2*)(ws + L3S_OFF);
    for (int s2 = threadIdx.x; s2 < 256; s2 += NTHR) {
        uint32_t c = ws[L3C_OFF + s2];
        uint32_t p = atomicAdd(&tc, c);   // LDS atomic
        for (uint32_t q = 0; q < c; ++q)
            if (p + q < L3TOT_CAP) l3s[p + q] = l3seg[(size_t)s2 * L3SEG_CAP + q];
    }
    if (threadIdx.x == 0) {
        uint32_t c = ws[SCL_OFF + 6]; if (c > OVL3_CAP) c = OVL3_CAP;
        uint32_t p = atomicAdd(&tc, c);
        const uint2* ovl3 = (const uint2*)(ws + OVL3_OFF);
        for (uint32_t q = 0; q < c; ++q)
            if (p + q < L3TOT_CAP) l3s[p + q] = ovl3[q];
    }
    __syncthreads();
    uint32_t c3 = tc < L3TOT_CAP ? tc : L3TOT_CAP;
    // scan my 8 pair segments: above sub-bin -> restore; in-bin -> exact rank
    const uint2* pairs = (const uint2*)(ws + PAIRS_OFF);
    for (int g = 0; g < NBLK_MAIN / 256; ++g) {
        uint32_t sidx = blockIdx.x + (uint32_t)g * 256u;
        uint32_t c = ws[PCN_OFF + sidx];
        const uint2* seg = pairs + (size_t)sidx * SEG_CAP;
        for (uint32_t i = threadIdx.x; i < c; i += NTHR) {
            uint2 pr = seg[i];
            uint32_t u = pr.x & MASK31;
            if (u >= tHi2) {
                out[pr.y] = pr.x;
            } else if (u - base2 < width) {
                uint32_t rank = 0;
                for (uint32_t p = 0; p < c3; ++p) {
                    uint2 q2 = l3s[p];
                    uint32_t up = q2.x & MASK31;
                    rank += (up > u || (up == u && q2.y < pr.y)) ? 1u : 0u;
                }
                if (rank < rem2) out[pr.y] = pr.x;
            }
        }
    }
    if (blockIdx.x == 0) {   // overflow pairs
        uint32_t c = ws[SCL_OFF + 5]; if (c > OVFP_CAP) c = OVFP_CAP;
        const uint2* ovfp = (const uint2*)(ws + OVFP_OFF);
        for (uint32_t i = threadIdx.x; i < c; i += NTHR) {
            uint2 pr = ovfp[i];
            uint32_t u = pr.x & MASK31;
            if (u >= tHi2) {
                out[pr.y] = pr.x;
            } else if (u - base2 < width) {
                uint32_t rank = 0;
                for (uint32_t p = 0; p < c3; ++p) {
                    uint2 q2 = l3s[p];
                    uint32_t up = q2.x & MASK31;
                    rank += (up > u || (up == u && q2.y < pr.y)) ? 1u : 0u;
                }
                if (rank < rem2) out[pr.y] = pr.x;
            }
        }
    }
}

extern "C" void kernel_launch(void* const* d_in, const int* in_sizes, int n_in,
                              void* d_out, int out_size, void* d_ws, size_t ws_size,
                              hipStream_t stream) {
    const uint32_t* x = (const uint32_t*)d_in[0];
    uint32_t* out = (uint32_t*)d_out;
    uint32_t* ws = (uint32_t*)d_ws;
    long long n = (long long)in_sizes[0];

    const double ratio = 0.5;  // SPARSE_COMPRESSION_RATIO
    long long k = (long long)((double)n * (1.0 - ratio));
    if (k < 1) k = 1;
    if (k > n) k = n;

    long long n4 = n >> 2;
    long long S4 = n4 >> 3;
    long long S = S4 << 2;                   // sampled elements (1/8 of n)
    long long ks = (long long)((double)k * ((double)S / (double)n));
    const long long M = 9216;                // ~9 sigma at S=4,194,304
    uint32_t ksmM = (uint32_t)((ks - M) < 1 ? 1 : (ks - M));
    uint32_t kspM = (uint32_t)((ks + M) > S ? S : (ks + M));

    zero_ws_kernel<<<(ZERO_WORDS + NTHR - 1) / NTHR, NTHR, 0, stream>>>(ws);
    sample_hist_kernel<<<256, NTHR, 0, stream>>>((const v4u*)x, n4, ws);
    sel_bracket_kernel<<<1, NTHR, 0, stream>>>(ws, ksmM, kspM);
    fused_main_kernel<<<NBLK_MAIN, NTHR, 0, stream>>>(x, out, n, ws);
    cand_hist_kernel<<<256, NTHR, 0, stream>>>(ws);
    sel_gather_kernel<<<256, NTHR, 0, stream>>>(ws, (uint32_t)k);
    final_fixup_kernel<<<256, NTHR, 0, stream>>>(ws, out);
}